// Round 14
// baseline (243.916 us; speedup 1.0000x reference)
//
#include <hip/hip_runtime.h>
#include <math.h>

#define B_ 4
#define N_ 2048
#define H_ 128
#define K_ 32
#define L_ 4
#define OUT_ 6
#define BN_ (B_*N_)
#define NPB_L 16               // nodes per block: layer kernel
#define LBLK 512               // threads per layer block (8 waves)

typedef __attribute__((ext_vector_type(8))) short short8;
typedef __attribute__((ext_vector_type(4))) float f32x4;

#define LDW (H_ + 8)           // padded LDS row (bf16 elems)
#define LAYER_W 98304          // shorts/layer: w1a 16K | w1c 16K | w2 16K | u1 32K | u2 16K
#define OFF_W1A 0
#define OFF_W1C 16384
#define OFF_W2  32768
#define OFF_U1  49152
#define OFF_U2  81920
#define SCAP 256
#define KNN_ROWS 4
#define KNN_BLKS (BN_/KNN_ROWS)          // 2048
#define PREP_BLKS (L_*LAYER_W/256)       // 1536

__device__ __forceinline__ float silu_f(float x) {
    return __fdividef(x, 1.0f + __expf(-x));
}
__device__ __forceinline__ short f2b(float f) {          // fp32 -> bf16 RNE
    unsigned u = __float_as_uint(f);
    return (short)((u + 0x7FFFu + ((u >> 16) & 1u)) >> 16);
}
__device__ __forceinline__ float b2f(short s) {
    return __uint_as_float(((unsigned)(unsigned short)s) << 16);
}
__device__ __forceinline__ unsigned pack2(short lo, short hi) {
    return (unsigned)(unsigned short)lo | ((unsigned)(unsigned short)hi << 16);
}
__device__ __forceinline__ int mbcnt64(unsigned long long m) {
    return __builtin_amdgcn_mbcnt_hi((unsigned)(m >> 32),
           __builtin_amdgcn_mbcnt_lo((unsigned)m, 0));
}

// ---------------- k_front: knn | weight prep | E-prep ----------------
// blocks [0,2048): knn. [2048,3584): wt transpose. 3584: fused layer-0 E mats.
__global__ __launch_bounds__(256) void k_front(
    const float* __restrict__ x, int* __restrict__ nidx, float* __restrict__ ndist,
    const float* __restrict__ miw, const float* __restrict__ mow,
    const float* __restrict__ uiw, const float* __restrict__ uow,
    short* __restrict__ wt,
    const float* __restrict__ ew, const float* __restrict__ eb,
    const float* __restrict__ mib, float* __restrict__ Epack)
{
    __shared__ float xsx[N_], xsy[N_], xsz[N_];          // 24 KB
    __shared__ unsigned skey[KNN_ROWS][SCAP];            // 4 KB
    __shared__ int      sid [KNN_ROWS][SCAP];            // 4 KB

    if (blockIdx.x >= KNN_BLKS + PREP_BLKS) {
        // ---- E-prep: Ea = ew@W1a(l0), ea = eb@W1a + b1 ; Ec/ec likewise ----
        int t = threadIdx.x;                 // 256 threads: which = a/c, n = col
        int which = t >> 7, n = t & 127;
        const float* W = miw + (size_t)(which ? 128 : 0) * H_;   // l=0 rows
        float E0 = 0.f, E1 = 0.f, E2 = 0.f, Eb = 0.f;
        for (int k = 0; k < 128; ++k) {
            float w = W[(size_t)k*H_ + n];
            E0 = fmaf(ew[k],       w, E0);
            E1 = fmaf(ew[128 + k], w, E1);
            E2 = fmaf(ew[256 + k], w, E2);
            Eb = fmaf(eb[k],       w, Eb);
        }
        float* dst = Epack + which * 512;    // [Ea(384)|ea(128)|Ec(384)|ec(128)]
        dst[0*128 + n] = E0;
        dst[1*128 + n] = E1;
        dst[2*128 + n] = E2;
        dst[3*128 + n] = Eb + (which ? 0.f : mib[n]);
        return;
    }
    if (blockIdx.x >= KNN_BLKS) {
        // ---- prep: transpose+cast all layer weights to bf16 [n][k] ----
        int gid = (blockIdx.x - KNN_BLKS) * 256 + threadIdx.x;
        int l = gid / LAYER_W, o = gid - l * LAYER_W;
        float v;
        if (o < OFF_W1C) {
            int n = o >> 7, k = o & 127;
            v = miw[(size_t)l*257*H_ + k*H_ + n];
        } else if (o < OFF_W2) {
            int oo = o - OFF_W1C, n = oo >> 7, k = oo & 127;
            v = miw[(size_t)l*257*H_ + (128 + k)*H_ + n];
        } else if (o < OFF_U1) {
            int oo = o - OFF_W2, n = oo >> 7, k = oo & 127;
            v = mow[(size_t)l*H_*H_ + k*H_ + n];
        } else if (o < OFF_U2) {
            int oo = o - OFF_U1, n = oo >> 8, k = oo & 255;
            v = uiw[(size_t)l*2*H_*H_ + k*H_ + n];
        } else {
            int oo = o - OFF_U2, n = oo >> 7, k = oo & 127;
            v = uow[(size_t)l*H_*H_ + k*H_ + n];
        }
        wt[gid] = f2b(v);
        return;
    }

    // ---- knn: 3-stage ballot select of K smallest d^2 per row ----
    int b  = blockIdx.x / (N_/KNN_ROWS);
    int i0 = (blockIdx.x % (N_/KNN_ROWS)) * KNN_ROWS;
    const float* xb = x + (size_t)b*N_*3;
    for (int t = threadIdx.x; t < N_*3; t += 256) {
        float v = xb[t];
        int q = t / 3, r = t - q*3;
        float* dst = (r == 0) ? xsx : (r == 1) ? xsy : xsz;
        dst[q] = v;
    }
    __syncthreads();

    int wave = threadIdx.x >> 6, lane = threadIdx.x & 63;
    int i = i0 + wave;
    float xix = xsx[i], xiy = xsy[i], xiz = xsz[i];

    unsigned u[N_/64];
    unsigned lmin = 0xFFFFFFFFu;
#pragma unroll
    for (int t = 0; t < N_/64; ++t) {
        int j = lane + 64*t;
        float d0 = xix-xsx[j], d1 = xiy-xsy[j], d2 = xiz-xsz[j];
        float d = d0*d0 + d1*d1 + d2*d2;
        unsigned k = (j == i) ? 0x7F800000u : __float_as_uint(d);
        u[t] = k;
        lmin = min(lmin, k);
    }
    // wave min/max of lane minima -> common prefix (exact bit-search narrowing)
    unsigned mn = lmin, mx = lmin;
    for (int off = 32; off; off >>= 1) {
        unsigned o1 = (unsigned)__shfl_xor((int)mn, off); mn = min(mn, o1);
        unsigned o2 = (unsigned)__shfl_xor((int)mx, off); mx = max(mx, o2);
    }
    unsigned Tup = mn;
    if (mn != mx) {
        int hb = 31 - __clz((int)(mn ^ mx));
        Tup = mn & ~((2u << hb) - 1u);
        for (int bit = hb; bit >= 0; --bit) {
            unsigned cand = Tup | (1u << bit);
            if (__popcll(__ballot(lmin < cand)) < K_) Tup = cand;
        }
    }
    unsigned* sk = skey[wave];
    int*      si = sid [wave];
    int base = 0;
#pragma unroll
    for (int t = 0; t < N_/64; ++t) {
        bool pr = (u[t] <= Tup);
        unsigned long long m = __ballot(pr);
        if (pr) {
            int pos = base + mbcnt64(m);
            if (pos < SCAP) { sk[pos] = u[t]; si[pos] = lane + 64*t; }
        }
        base += __popcll(m);
    }
    int c = min(base, SCAP);
    unsigned sv[4]; int iv[4];
#pragma unroll
    for (int q = 0; q < 4; ++q) {
        int slot = lane + 64*q;
        bool ok = slot < c;
        sv[q] = ok ? sk[slot] : 0xFFFFFFFFu;
        iv[q] = ok ? si[slot] : 0;
    }
    // exact K-th among survivors; answer in [mn, Tup] -> narrowed search
    unsigned T = mn;
    if (mn != Tup) {
        int hb = 31 - __clz((int)(mn ^ Tup));
        T = mn & ~((2u << hb) - 1u);
        for (int bit = hb; bit >= 0; --bit) {
            unsigned cand = T | (1u << bit);
            int cnt = __popcll(__ballot(sv[0] < cand)) + __popcll(__ballot(sv[1] < cand))
                    + __popcll(__ballot(sv[2] < cand)) + __popcll(__ballot(sv[3] < cand));
            if (cnt < K_) T = cand;
        }
    }
    int cnt_lt = __popcll(__ballot(sv[0] < T)) + __popcll(__ballot(sv[1] < T))
               + __popcll(__ballot(sv[2] < T)) + __popcll(__ballot(sv[3] < T));
    int need = K_ - cnt_lt;
    size_t rbase = ((size_t)(b*N_ + i)) * K_;
    int ltc = 0, eqc = 0;
#pragma unroll
    for (int q = 0; q < 4; ++q) {
        bool lt = sv[q] < T, eq = sv[q] == T;
        unsigned long long mlt = __ballot(lt), meq = __ballot(eq);
        int pp = ltc + mbcnt64(mlt), ee = eqc + mbcnt64(meq);
        ltc += __popcll(mlt); eqc += __popcll(meq);
        int pos = lt ? pp : ((eq && ee < need) ? (cnt_lt + ee) : -1);
        if (pos >= 0) {
            nidx [rbase + pos] = iv[q];
            ndist[rbase + pos] = sqrtf(__uint_as_float(sv[q]));
        }
    }
}

// ---------------- k_layer: [embed|stage] + edge + 3 GEMMs + residual + ac(l+1) [+ out] ----------------
// 16 nodes/block, 512 threads (8 waves); grid 512 = 2 blocks/CU.
// l==0 (is_l0): h computed in-block from x (bit-identical to old embed); edge
// uses fp32 a/c via fused E mats and 12B x_j LDS stage -> no c gathers at all.
// l>=1: R13 path (32 gathers in flight per node, residual from LDS).
__global__ __launch_bounds__(LBLK, 4) void k_layer(
    float* __restrict__ h, short* __restrict__ a,
    const int* __restrict__ nidx, const float* __restrict__ ndist,
    const float* __restrict__ wd,
    const short* __restrict__ wl,          // layer weights base (wt + l*LAYER_W)
    const float* __restrict__ b2, const float* __restrict__ u1b,
    const float* __restrict__ u2b,
    const short* __restrict__ c_rd, short* __restrict__ c_wr,
    const short* __restrict__ wn, const float* __restrict__ b1n, int do_ac,
    const float* __restrict__ ow, const float* __restrict__ ob,
    float* __restrict__ out,
    const float* __restrict__ x, const float* __restrict__ ew,
    const float* __restrict__ eb, const float* __restrict__ Epack, int is_l0)
{
    __shared__ __align__(16) short s_l[NPB_L][LDW];    // edge silu-sum; reused for t1
    __shared__ __align__(16) short h_l[NPB_L][LDW];    // bf16 h (old, then new)
    __shared__ __align__(16) short agg_l[NPB_L][LDW];
    __shared__ __align__(16) float h32s[NPB_L][H_];    // fp32 h (residual source)
    __shared__ float xjs[NPB_L][K_][3];                // l0: neighbor coords (6 KB)
    __shared__ int   idx_s[NPB_L][K_];
    __shared__ float dst_s[NPB_L][K_];
    // XCD swizzle: batch = (blk&7)>>1, sub = (blk>>3)*2 + (blk&1)
    int blk = blockIdx.x;
    int batch = (blk & 7) >> 1;
    int sub   = ((blk >> 3) << 1) | (blk & 1);
    int node0 = batch * N_ + sub * NPB_L;
    int tid = threadIdx.x;
    int wave = tid >> 6, lane = tid & 63, l15 = lane & 15, quad = lane >> 4;
    int ncol = wave*16 + l15;               // this wave's output column

    // ---- staging (pre-barrier) ----
    if (is_l0) {
        // embed own nodes: h_l (bf16) + h32s (fp32), identical arithmetic to old k_embed_ac
        for (int t = tid; t < NPB_L*H_; t += LBLK) {
            int row = t >> 7, ch = t & 127;
            int gr = node0 + row;
            float v = eb[ch];
            v = fmaf(x[gr*3+0], ew[ch], v);
            v = fmaf(x[gr*3+1], ew[H_+ch], v);
            v = fmaf(x[gr*3+2], ew[2*H_+ch], v);
            h_l[row][ch] = f2b(v);
            h32s[row][ch] = v;
        }
    } else {
        float4 v = reinterpret_cast<const float4*>(h + (size_t)node0*H_)[tid];
        int row = tid >> 5, col = (tid & 31) * 4;
        h_l[row][col+0] = f2b(v.x); h_l[row][col+1] = f2b(v.y);
        h_l[row][col+2] = f2b(v.z); h_l[row][col+3] = f2b(v.w);
        *(float4*)&h32s[row][col] = v;
    }
    {
        int j = nidx[(size_t)node0*K_ + tid];      // 512 threads = 16x32 (m,k)
        int sm = tid >> 5, sk = tid & 31;
        idx_s[sm][sk] = j;
        dst_s[sm][sk] = ndist[(size_t)node0*K_ + tid];
        if (is_l0) {
            const float* xp = x + ((size_t)batch*N_ + j)*3;
            xjs[sm][sk][0] = xp[0]; xjs[sm][sk][1] = xp[1]; xjs[sm][sk][2] = xp[2];
        }
    }
    __syncthreads();

    // prefetch all GEMM B-operands
    short8 bw2[4], bu1[8], bu2[4];
#pragma unroll
    for (int kk = 0; kk < 4; ++kk)
        bw2[kk] = *(const short8*)(wl + OFF_W2 + (size_t)ncol*H_ + kk*32 + quad*8);
#pragma unroll
    for (int kk = 0; kk < 8; ++kk)
        bu1[kk] = *(const short8*)(wl + OFF_U1 + (size_t)ncol*2*H_ + kk*32 + quad*8);
#pragma unroll
    for (int kk = 0; kk < 4; ++kk)
        bu2[kk] = *(const short8*)(wl + OFF_U2 + (size_t)ncol*H_ + kk*32 + quad*8);

    // ---- edge phase ----
    {
        float wd0 = wd[2*lane], wd1 = wd[2*lane+1];
        int ch0 = 2*lane, ch1 = 2*lane + 1;
        if (is_l0) {
            // fp32 a/c from fused E mats; neighbor data = 3 floats from LDS
            float Ea00 = Epack[ch0],       Ea01 = Epack[ch1];
            float Ea10 = Epack[128+ch0],   Ea11 = Epack[128+ch1];
            float Ea20 = Epack[256+ch0],   Ea21 = Epack[256+ch1];
            float ea0  = Epack[384+ch0],   ea1  = Epack[384+ch1];
            float Ec00 = Epack[512+ch0],   Ec01 = Epack[512+ch1];
            float Ec10 = Epack[640+ch0],   Ec11 = Epack[640+ch1];
            float Ec20 = Epack[768+ch0],   Ec21 = Epack[768+ch1];
            float ec0  = Epack[896+ch0],   ec1  = Epack[896+ch1];
#pragma unroll
            for (int nn = 0; nn < 2; ++nn) {
                int m = wave*2 + nn;
                int gr = node0 + m;
                float xi0 = x[gr*3], xi1 = x[gr*3+1], xi2 = x[gr*3+2];
                float a0 = fmaf(xi2, Ea20, fmaf(xi1, Ea10, fmaf(xi0, Ea00, ea0)));
                float a1 = fmaf(xi2, Ea21, fmaf(xi1, Ea11, fmaf(xi0, Ea01, ea1)));
                float s0 = 0.f, s1 = 0.f;
#pragma unroll
                for (int k = 0; k < K_; ++k) {
                    float xj0 = xjs[m][k][0], xj1 = xjs[m][k][1], xj2 = xjs[m][k][2];
                    float dd = dst_s[m][k];
                    float c0 = fmaf(xj2, Ec20, fmaf(xj1, Ec10, fmaf(xj0, Ec00, ec0)));
                    float c1 = fmaf(xj2, Ec21, fmaf(xj1, Ec11, fmaf(xj0, Ec01, ec1)));
                    s0 += silu_f(a0 + fmaf(dd, wd0, c0));
                    s1 += silu_f(a1 + fmaf(dd, wd1, c1));
                }
                *(unsigned*)&s_l[m][2*lane] = pack2(f2b(s0), f2b(s1));
            }
        } else {
            const unsigned* c2 = (const unsigned*)c_rd + (size_t)batch*N_*(H_/2);
            const unsigned* a2 = (const unsigned*)a;
#pragma unroll
            for (int nn = 0; nn < 2; ++nn) {
                int m = wave*2 + nn;
                unsigned av = a2[(size_t)(node0+m)*(H_/2) + lane];
                float a0 = b2f((short)(av & 0xFFFFu)), a1 = b2f((short)(av >> 16));
                unsigned cva[16], cvb[16];
#pragma unroll
                for (int k = 0; k < 16; ++k)
                    cva[k] = c2[(size_t)idx_s[m][k]*(H_/2) + lane];
#pragma unroll
                for (int k = 0; k < 16; ++k)
                    cvb[k] = c2[(size_t)idx_s[m][16+k]*(H_/2) + lane];
                float s0 = 0.f, s1 = 0.f;
#pragma unroll
                for (int k = 0; k < 16; ++k) {
                    float dd = dst_s[m][k];
                    s0 += silu_f(a0 + fmaf(dd, wd0, b2f((short)(cva[k] & 0xFFFFu))));
                    s1 += silu_f(a1 + fmaf(dd, wd1, b2f((short)(cva[k] >> 16))));
                }
#pragma unroll
                for (int k = 0; k < 16; ++k) {
                    float dd = dst_s[m][16+k];
                    s0 += silu_f(a0 + fmaf(dd, wd0, b2f((short)(cvb[k] & 0xFFFFu))));
                    s1 += silu_f(a1 + fmaf(dd, wd1, b2f((short)(cvb[k] >> 16))));
                }
                *(unsigned*)&s_l[m][2*lane] = pack2(f2b(s0), f2b(s1));
            }
        }
    }
    __syncthreads();

    f32x4 acc;
    // ---- GEMM1: agg = s @ w2 + K*b2 -> agg_l ----
    acc = (f32x4){0,0,0,0};
#pragma unroll
    for (int kk = 0; kk < 4; ++kk) {
        int k0 = kk*32 + quad*8;
        short8 af = *(const short8*)&s_l[l15][k0];
        acc = __builtin_amdgcn_mfma_f32_16x16x32_bf16(af, bw2[kk], acc, 0, 0, 0);
    }
    {
        float b2v = b2[ncol] * (float)K_;
#pragma unroll
        for (int r = 0; r < 4; ++r)
            agg_l[quad*4 + r][ncol] = f2b(acc[r] + b2v);
    }
    __syncthreads();

    // ---- GEMM2: t1 = silu([h | agg] @ u1 + u1b) -> s_l ----
    acc = (f32x4){0,0,0,0};
#pragma unroll
    for (int kk = 0; kk < 8; ++kk) {
        const short (*src)[LDW] = (kk < 4) ? h_l : agg_l;
        int kloc = ((kk < 4) ? kk*32 : (kk-4)*32) + quad*8;
        short8 af = *(const short8*)&src[l15][kloc];
        acc = __builtin_amdgcn_mfma_f32_16x16x32_bf16(af, bu1[kk], acc, 0, 0, 0);
    }
    // prefetch ac weights (overlap GEMM3 + barriers)
    short8 bacA[4], bacC[4];
    if (do_ac) {
#pragma unroll
        for (int kk = 0; kk < 4; ++kk) {
            bacA[kk] = *(const short8*)(wn + OFF_W1A + (size_t)ncol*H_ + kk*32 + quad*8);
            bacC[kk] = *(const short8*)(wn + OFF_W1C + (size_t)ncol*H_ + kk*32 + quad*8);
        }
    }
    {
        float u1bv = u1b[ncol];
#pragma unroll
        for (int r = 0; r < 4; ++r)
            s_l[quad*4 + r][ncol] = f2b(silu_f(acc[r] + u1bv));
    }
    __syncthreads();

    // ---- GEMM3: upd = t1 @ u2 + u2b ; h(from LDS) += upd ; store global h ----
    acc = (f32x4){0,0,0,0};
#pragma unroll
    for (int kk = 0; kk < 4; ++kk) {
        int k0 = kk*32 + quad*8;
        short8 af = *(const short8*)&s_l[l15][k0];
        acc = __builtin_amdgcn_mfma_f32_16x16x32_bf16(af, bu2[kk], acc, 0, 0, 0);
    }
    {
        float u2bv = u2b[ncol];
#pragma unroll
        for (int r = 0; r < 4; ++r) {
            int m = quad*4 + r;
            float nh = h32s[m][ncol] + acc[r] + u2bv;   // residual from LDS
            h[(size_t)(node0+m)*H_ + ncol] = nh;        // store-only
            if (do_ac) h_l[m][ncol] = f2b(nh);
            else       h32s[m][ncol] = nh;              // each (m,ncol) owned by one lane
        }
    }
    if (do_ac) {
        // ---- ac(l+1): a -> global, c -> c_wr (other parity buffer) ----
        __syncthreads();
        int n = ncol;
        f32x4 accA = (f32x4){0,0,0,0}, accC = (f32x4){0,0,0,0};
#pragma unroll
        for (int kk = 0; kk < 4; ++kk) {
            int k0 = kk*32 + quad*8;
            short8 af = *(const short8*)&h_l[l15][k0];
            accA = __builtin_amdgcn_mfma_f32_16x16x32_bf16(af, bacA[kk], accA, 0, 0, 0);
            accC = __builtin_amdgcn_mfma_f32_16x16x32_bf16(af, bacC[kk], accC, 0, 0, 0);
        }
        float b1v = b1n[n];
#pragma unroll
        for (int r = 0; r < 4; ++r) {
            int m = quad*4 + r;
            size_t gi = (size_t)(node0+m)*H_ + n;
            a[gi]    = f2b(accA[r] + b1v);
            c_wr[gi] = f2b(accC[r]);
        }
    } else {
        // ---- last layer: out = h @ ow + ob (fp32, from LDS) ----
        __syncthreads();
        if (tid < NPB_L*OUT_) {
            int node = tid / OUT_, o = tid - node*OUT_;
            float accv = ob[o];
            for (int r = 0; r < H_; ++r)
                accv = fmaf(h32s[node][r], ow[r*OUT_ + o], accv);
            out[(size_t)(node0+node)*OUT_ + o] = accv;
        }
    }
}

extern "C" void kernel_launch(void* const* d_in, const int* in_sizes, int n_in,
                              void* d_out, int out_size, void* d_ws, size_t ws_size,
                              hipStream_t stream)
{
    const float* x   = (const float*)d_in[0];
    const float* ew  = (const float*)d_in[1];
    const float* eb  = (const float*)d_in[2];
    const float* miw = (const float*)d_in[3];
    const float* mib = (const float*)d_in[4];
    const float* mow = (const float*)d_in[5];
    const float* mob = (const float*)d_in[6];
    const float* uiw = (const float*)d_in[7];
    const float* uib = (const float*)d_in[8];
    const float* uow = (const float*)d_in[9];
    const float* uob = (const float*)d_in[10];
    const float* ow  = (const float*)d_in[11];
    const float* ob  = (const float*)d_in[12];
    float* out = (float*)d_out;

    // workspace: h fp32 | nd fp32 | ni i32 | a bf16 | c0 bf16 | c1 bf16 | wt bf16 | Epack fp32
    char* w = (char*)d_ws;
    float* h  = (float*)w;                         w += (size_t)BN_*H_*4;
    float* nd = (float*)w;                         w += (size_t)BN_*K_*4;
    int*   ni = (int*)w;                           w += (size_t)BN_*K_*4;
    short* a  = (short*)w;                         w += (size_t)BN_*H_*2;
    short* c0 = (short*)w;                         w += (size_t)BN_*H_*2;
    short* c1 = (short*)w;                         w += (size_t)BN_*H_*2;
    short* wt = (short*)w;                         w += (size_t)L_*LAYER_W*2;
    float* Epack = (float*)w;                                               // 4 KB

    k_front<<<KNN_BLKS + PREP_BLKS + 1, 256, 0, stream>>>(x, ni, nd,
        miw, mow, uiw, uow, wt, ew, eb, mib, Epack);
    for (int l = 0; l < L_; ++l) {
        const short* c_rd = (l & 1) ? c1 : c0;
        short*       c_wr = (l & 1) ? c0 : c1;
        int do_ac = (l + 1 < L_);
        const short* wn = wt + (size_t)(do_ac ? (l+1) : l) * LAYER_W;
        const float* b1n = mib + (size_t)(do_ac ? (l+1) : l) * H_;
        k_layer<<<BN_/NPB_L, LBLK, 0, stream>>>(h, a, ni, nd,
            miw + (size_t)l*257*H_ + 256*H_,
            wt + (size_t)l*LAYER_W,
            mob + (size_t)l*H_, uib + (size_t)l*H_, uob + (size_t)l*H_,
            c_rd, c_wr, wn, b1n, do_ac,
            ow, ob, out,
            x, ew, eb, Epack, (l == 0) ? 1 : 0);
    }
}

// Round 15
// 222.891 us; speedup vs baseline: 1.0943x; 1.0943x over previous
//
#include <hip/hip_runtime.h>
#include <math.h>

#define B_ 4
#define N_ 2048
#define H_ 128
#define K_ 32
#define L_ 4
#define OUT_ 6
#define BN_ (B_*N_)
#define NPB_L 16               // nodes per block: layer kernels
#define LBLK 512               // threads per layer block (8 waves)

typedef __attribute__((ext_vector_type(8))) short short8;
typedef __attribute__((ext_vector_type(4))) float f32x4;

#define LDW (H_ + 8)           // padded LDS row (bf16 elems)
#define LAYER_W 98304          // shorts/layer: w1a 16K | w1c 16K | w2 16K | u1 32K | u2 16K
#define OFF_W1A 0
#define OFF_W1C 16384
#define OFF_W2  32768
#define OFF_U1  49152
#define OFF_U2  81920
#define SCAP 256
#define KNN_ROWS 4
#define KNN_BLKS (BN_/KNN_ROWS)          // 2048
#define PREP_BLKS (L_*LAYER_W/256)       // 1536

__device__ __forceinline__ float silu_f(float x) {
    return __fdividef(x, 1.0f + __expf(-x));
}
__device__ __forceinline__ short f2b(float f) {          // fp32 -> bf16 RNE
    unsigned u = __float_as_uint(f);
    return (short)((u + 0x7FFFu + ((u >> 16) & 1u)) >> 16);
}
__device__ __forceinline__ float b2f(short s) {
    return __uint_as_float(((unsigned)(unsigned short)s) << 16);
}
__device__ __forceinline__ unsigned pack2(short lo, short hi) {
    return (unsigned)(unsigned short)lo | ((unsigned)(unsigned short)hi << 16);
}
__device__ __forceinline__ int mbcnt64(unsigned long long m) {
    return __builtin_amdgcn_mbcnt_hi((unsigned)(m >> 32),
           __builtin_amdgcn_mbcnt_lo((unsigned)m, 0));
}

// ---------------- k_front: knn | weight prep | E-prep ----------------
__global__ __launch_bounds__(256) void k_front(
    const float* __restrict__ x, int* __restrict__ nidx, float* __restrict__ ndist,
    const float* __restrict__ miw, const float* __restrict__ mow,
    const float* __restrict__ uiw, const float* __restrict__ uow,
    short* __restrict__ wt,
    const float* __restrict__ ew, const float* __restrict__ eb,
    const float* __restrict__ mib, float* __restrict__ Epack)
{
    __shared__ float xsx[N_], xsy[N_], xsz[N_];          // 24 KB
    __shared__ unsigned skey[KNN_ROWS][SCAP];            // 4 KB
    __shared__ int      sid [KNN_ROWS][SCAP];            // 4 KB

    if (blockIdx.x >= KNN_BLKS + PREP_BLKS) {
        // ---- E-prep: Ea = ew@W1a(l0), ea = eb@W1a + b1 ; Ec/ec likewise ----
        int t = threadIdx.x;                 // 256 threads: which = a/c, n = col
        int which = t >> 7, n = t & 127;
        const float* W = miw + (size_t)(which ? 128 : 0) * H_;   // l=0 rows
        float E0 = 0.f, E1 = 0.f, E2 = 0.f, Eb = 0.f;
        for (int k = 0; k < 128; ++k) {
            float w = W[(size_t)k*H_ + n];
            E0 = fmaf(ew[k],       w, E0);
            E1 = fmaf(ew[128 + k], w, E1);
            E2 = fmaf(ew[256 + k], w, E2);
            Eb = fmaf(eb[k],       w, Eb);
        }
        float* dst = Epack + which * 512;    // [Ea(384)|ea(128)|Ec(384)|ec(128)]
        dst[0*128 + n] = E0;
        dst[1*128 + n] = E1;
        dst[2*128 + n] = E2;
        dst[3*128 + n] = Eb + (which ? 0.f : mib[n]);
        return;
    }
    if (blockIdx.x >= KNN_BLKS) {
        // ---- prep: transpose+cast all layer weights to bf16 [n][k] ----
        int gid = (blockIdx.x - KNN_BLKS) * 256 + threadIdx.x;
        int l = gid / LAYER_W, o = gid - l * LAYER_W;
        float v;
        if (o < OFF_W1C) {
            int n = o >> 7, k = o & 127;
            v = miw[(size_t)l*257*H_ + k*H_ + n];
        } else if (o < OFF_W2) {
            int oo = o - OFF_W1C, n = oo >> 7, k = oo & 127;
            v = miw[(size_t)l*257*H_ + (128 + k)*H_ + n];
        } else if (o < OFF_U1) {
            int oo = o - OFF_W2, n = oo >> 7, k = oo & 127;
            v = mow[(size_t)l*H_*H_ + k*H_ + n];
        } else if (o < OFF_U2) {
            int oo = o - OFF_U1, n = oo >> 8, k = oo & 255;
            v = uiw[(size_t)l*2*H_*H_ + k*H_ + n];
        } else {
            int oo = o - OFF_U2, n = oo >> 7, k = oo & 127;
            v = uow[(size_t)l*H_*H_ + k*H_ + n];
        }
        wt[gid] = f2b(v);
        return;
    }

    // ---- knn: 3-stage ballot select of K smallest d^2 per row ----
    int b  = blockIdx.x / (N_/KNN_ROWS);
    int i0 = (blockIdx.x % (N_/KNN_ROWS)) * KNN_ROWS;
    const float* xb = x + (size_t)b*N_*3;
    for (int t = threadIdx.x; t < N_*3; t += 256) {
        float v = xb[t];
        int q = t / 3, r = t - q*3;
        float* dst = (r == 0) ? xsx : (r == 1) ? xsy : xsz;
        dst[q] = v;
    }
    __syncthreads();

    int wave = threadIdx.x >> 6, lane = threadIdx.x & 63;
    int i = i0 + wave;
    float xix = xsx[i], xiy = xsy[i], xiz = xsz[i];

    unsigned u[N_/64];
    unsigned lmin = 0xFFFFFFFFu;
#pragma unroll
    for (int t = 0; t < N_/64; ++t) {
        int j = lane + 64*t;
        float d0 = xix-xsx[j], d1 = xiy-xsy[j], d2 = xiz-xsz[j];
        float d = d0*d0 + d1*d1 + d2*d2;
        unsigned k = (j == i) ? 0x7F800000u : __float_as_uint(d);
        u[t] = k;
        lmin = min(lmin, k);
    }
    // wave min/max of lane minima -> common prefix (exact bit-search narrowing)
    unsigned mn = lmin, mx = lmin;
    for (int off = 32; off; off >>= 1) {
        unsigned o1 = (unsigned)__shfl_xor((int)mn, off); mn = min(mn, o1);
        unsigned o2 = (unsigned)__shfl_xor((int)mx, off); mx = max(mx, o2);
    }
    unsigned Tup = mn;
    if (mn != mx) {
        int hb = 31 - __clz((int)(mn ^ mx));
        Tup = mn & ~((2u << hb) - 1u);
        for (int bit = hb; bit >= 0; --bit) {
            unsigned cand = Tup | (1u << bit);
            if (__popcll(__ballot(lmin < cand)) < K_) Tup = cand;
        }
    }
    unsigned* sk = skey[wave];
    int*      si = sid [wave];
    int base = 0;
#pragma unroll
    for (int t = 0; t < N_/64; ++t) {
        bool pr = (u[t] <= Tup);
        unsigned long long m = __ballot(pr);
        if (pr) {
            int pos = base + mbcnt64(m);
            if (pos < SCAP) { sk[pos] = u[t]; si[pos] = lane + 64*t; }
        }
        base += __popcll(m);
    }
    int c = min(base, SCAP);
    unsigned sv[4]; int iv[4];
#pragma unroll
    for (int q = 0; q < 4; ++q) {
        int slot = lane + 64*q;
        bool ok = slot < c;
        sv[q] = ok ? sk[slot] : 0xFFFFFFFFu;
        iv[q] = ok ? si[slot] : 0;
    }
    // exact K-th among survivors; answer in [mn, Tup] -> narrowed search
    unsigned T = mn;
    if (mn != Tup) {
        int hb = 31 - __clz((int)(mn ^ Tup));
        T = mn & ~((2u << hb) - 1u);
        for (int bit = hb; bit >= 0; --bit) {
            unsigned cand = T | (1u << bit);
            int cnt = __popcll(__ballot(sv[0] < cand)) + __popcll(__ballot(sv[1] < cand))
                    + __popcll(__ballot(sv[2] < cand)) + __popcll(__ballot(sv[3] < cand));
            if (cnt < K_) T = cand;
        }
    }
    int cnt_lt = __popcll(__ballot(sv[0] < T)) + __popcll(__ballot(sv[1] < T))
               + __popcll(__ballot(sv[2] < T)) + __popcll(__ballot(sv[3] < T));
    int need = K_ - cnt_lt;
    size_t rbase = ((size_t)(b*N_ + i)) * K_;
    int ltc = 0, eqc = 0;
#pragma unroll
    for (int q = 0; q < 4; ++q) {
        bool lt = sv[q] < T, eq = sv[q] == T;
        unsigned long long mlt = __ballot(lt), meq = __ballot(eq);
        int pp = ltc + mbcnt64(mlt), ee = eqc + mbcnt64(meq);
        ltc += __popcll(mlt); eqc += __popcll(meq);
        int pos = lt ? pp : ((eq && ee < need) ? (cnt_lt + ee) : -1);
        if (pos >= 0) {
            nidx [rbase + pos] = iv[q];
            ndist[rbase + pos] = sqrtf(__uint_as_float(sv[q]));
        }
    }
}

// ---------------- k_layer0: embed + fp32-E edge + GEMMs + residual + ac(1) ----------------
// Separate kernel so its register pressure does NOT pollute k_layer (R14 post-
// mortem: merging the l0 path regressed l>=1 by sinking the 32-deep gathers).
__global__ __launch_bounds__(LBLK, 4) void k_layer0(
    float* __restrict__ h, short* __restrict__ a,
    const int* __restrict__ nidx, const float* __restrict__ ndist,
    const float* __restrict__ wd,
    const short* __restrict__ wl,
    const float* __restrict__ b2, const float* __restrict__ u1b,
    const float* __restrict__ u2b,
    short* __restrict__ c_wr,
    const short* __restrict__ wn, const float* __restrict__ b1n,
    const float* __restrict__ x, const float* __restrict__ ew,
    const float* __restrict__ eb, const float* __restrict__ Epack)
{
    __shared__ __align__(16) short s_l[NPB_L][LDW];
    __shared__ __align__(16) short h_l[NPB_L][LDW];
    __shared__ __align__(16) short agg_l[NPB_L][LDW];
    __shared__ __align__(16) float h32s[NPB_L][H_];
    __shared__ float xjs[NPB_L][K_][3];
    __shared__ float dst_s[NPB_L][K_];
    int blk = blockIdx.x;
    int batch = (blk & 7) >> 1;
    int sub   = ((blk >> 3) << 1) | (blk & 1);
    int node0 = batch * N_ + sub * NPB_L;
    int tid = threadIdx.x;
    int wave = tid >> 6, lane = tid & 63, l15 = lane & 15, quad = lane >> 4;
    int ncol = wave*16 + l15;

    // embed own nodes (identical arithmetic to original k_embed_ac)
    for (int t = tid; t < NPB_L*H_; t += LBLK) {
        int row = t >> 7, ch = t & 127;
        int gr = node0 + row;
        float v = eb[ch];
        v = fmaf(x[gr*3+0], ew[ch], v);
        v = fmaf(x[gr*3+1], ew[H_+ch], v);
        v = fmaf(x[gr*3+2], ew[2*H_+ch], v);
        h_l[row][ch] = f2b(v);
        h32s[row][ch] = v;
    }
    {
        int j = nidx[(size_t)node0*K_ + tid];      // 512 threads = 16x32 (m,k)
        int sm = tid >> 5, sk = tid & 31;
        dst_s[sm][sk] = ndist[(size_t)node0*K_ + tid];
        const float* xp = x + ((size_t)batch*N_ + j)*3;
        xjs[sm][sk][0] = xp[0]; xjs[sm][sk][1] = xp[1]; xjs[sm][sk][2] = xp[2];
    }
    __syncthreads();

    // prefetch GEMM B-operands
    short8 bw2[4], bu1[8], bu2[4];
#pragma unroll
    for (int kk = 0; kk < 4; ++kk)
        bw2[kk] = *(const short8*)(wl + OFF_W2 + (size_t)ncol*H_ + kk*32 + quad*8);
#pragma unroll
    for (int kk = 0; kk < 8; ++kk)
        bu1[kk] = *(const short8*)(wl + OFF_U1 + (size_t)ncol*2*H_ + kk*32 + quad*8);
#pragma unroll
    for (int kk = 0; kk < 4; ++kk)
        bu2[kk] = *(const short8*)(wl + OFF_U2 + (size_t)ncol*H_ + kk*32 + quad*8);

    // ---- edge (fp32 a/c via fused E mats; no gathers) ----
    {
        float wd0 = wd[2*lane], wd1 = wd[2*lane+1];
        int ch0 = 2*lane, ch1 = 2*lane + 1;
        float Ea00 = Epack[ch0],       Ea01 = Epack[ch1];
        float Ea10 = Epack[128+ch0],   Ea11 = Epack[128+ch1];
        float Ea20 = Epack[256+ch0],   Ea21 = Epack[256+ch1];
        float ea0  = Epack[384+ch0],   ea1  = Epack[384+ch1];
        float Ec00 = Epack[512+ch0],   Ec01 = Epack[512+ch1];
        float Ec10 = Epack[640+ch0],   Ec11 = Epack[640+ch1];
        float Ec20 = Epack[768+ch0],   Ec21 = Epack[768+ch1];
        float ec0  = Epack[896+ch0],   ec1  = Epack[896+ch1];
#pragma unroll
        for (int nn = 0; nn < 2; ++nn) {
            int m = wave*2 + nn;
            int gr = node0 + m;
            float xi0 = x[gr*3], xi1 = x[gr*3+1], xi2 = x[gr*3+2];
            float a0 = fmaf(xi2, Ea20, fmaf(xi1, Ea10, fmaf(xi0, Ea00, ea0)));
            float a1 = fmaf(xi2, Ea21, fmaf(xi1, Ea11, fmaf(xi0, Ea01, ea1)));
            float s0 = 0.f, s1 = 0.f;
#pragma unroll
            for (int k = 0; k < K_; ++k) {
                float xj0 = xjs[m][k][0], xj1 = xjs[m][k][1], xj2 = xjs[m][k][2];
                float dd = dst_s[m][k];
                float c0 = fmaf(xj2, Ec20, fmaf(xj1, Ec10, fmaf(xj0, Ec00, ec0)));
                float c1 = fmaf(xj2, Ec21, fmaf(xj1, Ec11, fmaf(xj0, Ec01, ec1)));
                s0 += silu_f(a0 + fmaf(dd, wd0, c0));
                s1 += silu_f(a1 + fmaf(dd, wd1, c1));
            }
            *(unsigned*)&s_l[m][2*lane] = pack2(f2b(s0), f2b(s1));
        }
    }
    __syncthreads();

    f32x4 acc;
    // ---- GEMM1 ----
    acc = (f32x4){0,0,0,0};
#pragma unroll
    for (int kk = 0; kk < 4; ++kk) {
        int k0 = kk*32 + quad*8;
        short8 af = *(const short8*)&s_l[l15][k0];
        acc = __builtin_amdgcn_mfma_f32_16x16x32_bf16(af, bw2[kk], acc, 0, 0, 0);
    }
    {
        float b2v = b2[ncol] * (float)K_;
#pragma unroll
        for (int r = 0; r < 4; ++r)
            agg_l[quad*4 + r][ncol] = f2b(acc[r] + b2v);
    }
    __syncthreads();

    // ---- GEMM2 ----
    acc = (f32x4){0,0,0,0};
#pragma unroll
    for (int kk = 0; kk < 8; ++kk) {
        const short (*src)[LDW] = (kk < 4) ? h_l : agg_l;
        int kloc = ((kk < 4) ? kk*32 : (kk-4)*32) + quad*8;
        short8 af = *(const short8*)&src[l15][kloc];
        acc = __builtin_amdgcn_mfma_f32_16x16x32_bf16(af, bu1[kk], acc, 0, 0, 0);
    }
    short8 bacA[4], bacC[4];
#pragma unroll
    for (int kk = 0; kk < 4; ++kk) {
        bacA[kk] = *(const short8*)(wn + OFF_W1A + (size_t)ncol*H_ + kk*32 + quad*8);
        bacC[kk] = *(const short8*)(wn + OFF_W1C + (size_t)ncol*H_ + kk*32 + quad*8);
    }
    {
        float u1bv = u1b[ncol];
#pragma unroll
        for (int r = 0; r < 4; ++r)
            s_l[quad*4 + r][ncol] = f2b(silu_f(acc[r] + u1bv));
    }
    __syncthreads();

    // ---- GEMM3 + residual ----
    acc = (f32x4){0,0,0,0};
#pragma unroll
    for (int kk = 0; kk < 4; ++kk) {
        int k0 = kk*32 + quad*8;
        short8 af = *(const short8*)&s_l[l15][k0];
        acc = __builtin_amdgcn_mfma_f32_16x16x32_bf16(af, bu2[kk], acc, 0, 0, 0);
    }
    {
        float u2bv = u2b[ncol];
#pragma unroll
        for (int r = 0; r < 4; ++r) {
            int m = quad*4 + r;
            float nh = h32s[m][ncol] + acc[r] + u2bv;
            h[(size_t)(node0+m)*H_ + ncol] = nh;
            h_l[m][ncol] = f2b(nh);
        }
    }
    // ---- ac(1) ----
    __syncthreads();
    {
        int n = ncol;
        f32x4 accA = (f32x4){0,0,0,0}, accC = (f32x4){0,0,0,0};
#pragma unroll
        for (int kk = 0; kk < 4; ++kk) {
            int k0 = kk*32 + quad*8;
            short8 af = *(const short8*)&h_l[l15][k0];
            accA = __builtin_amdgcn_mfma_f32_16x16x32_bf16(af, bacA[kk], accA, 0, 0, 0);
            accC = __builtin_amdgcn_mfma_f32_16x16x32_bf16(af, bacC[kk], accC, 0, 0, 0);
        }
        float b1v = b1n[n];
#pragma unroll
        for (int r = 0; r < 4; ++r) {
            int m = quad*4 + r;
            size_t gi = (size_t)(node0+m)*H_ + n;
            a[gi]    = f2b(accA[r] + b1v);
            c_wr[gi] = f2b(accC[r]);
        }
    }
}

// ---------------- k_layer (l>=1): exact R13 body ----------------
__global__ __launch_bounds__(LBLK, 4) void k_layer(
    float* __restrict__ h, short* __restrict__ a,
    const int* __restrict__ nidx, const float* __restrict__ ndist,
    const float* __restrict__ wd,
    const short* __restrict__ wl,
    const float* __restrict__ b2, const float* __restrict__ u1b,
    const float* __restrict__ u2b,
    const short* __restrict__ c_rd, short* __restrict__ c_wr,
    const short* __restrict__ wn, const float* __restrict__ b1n, int do_ac,
    const float* __restrict__ ow, const float* __restrict__ ob,
    float* __restrict__ out)
{
    __shared__ __align__(16) short s_l[NPB_L][LDW];
    __shared__ __align__(16) short h_l[NPB_L][LDW];
    __shared__ __align__(16) short agg_l[NPB_L][LDW];
    __shared__ __align__(16) float h32s[NPB_L][H_];
    __shared__ int   idx_s[NPB_L][K_];
    __shared__ float dst_s[NPB_L][K_];
    int blk = blockIdx.x;
    int batch = (blk & 7) >> 1;
    int sub   = ((blk >> 3) << 1) | (blk & 1);
    int node0 = batch * N_ + sub * NPB_L;
    int tid = threadIdx.x;
    int wave = tid >> 6, lane = tid & 63, l15 = lane & 15, quad = lane >> 4;
    int ncol = wave*16 + l15;

    {
        float4 v = reinterpret_cast<const float4*>(h + (size_t)node0*H_)[tid];
        int row = tid >> 5, col = (tid & 31) * 4;
        h_l[row][col+0] = f2b(v.x); h_l[row][col+1] = f2b(v.y);
        h_l[row][col+2] = f2b(v.z); h_l[row][col+3] = f2b(v.w);
        *(float4*)&h32s[row][col] = v;
    }
    idx_s[tid>>5][tid&31] = nidx[(size_t)node0*K_ + tid];
    dst_s[tid>>5][tid&31] = ndist[(size_t)node0*K_ + tid];
    __syncthreads();

    short8 bw2[4], bu1[8], bu2[4];
#pragma unroll
    for (int kk = 0; kk < 4; ++kk)
        bw2[kk] = *(const short8*)(wl + OFF_W2 + (size_t)ncol*H_ + kk*32 + quad*8);
#pragma unroll
    for (int kk = 0; kk < 8; ++kk)
        bu1[kk] = *(const short8*)(wl + OFF_U1 + (size_t)ncol*2*H_ + kk*32 + quad*8);
#pragma unroll
    for (int kk = 0; kk < 4; ++kk)
        bu2[kk] = *(const short8*)(wl + OFF_U2 + (size_t)ncol*H_ + kk*32 + quad*8);

    // ---- edge: 32 gathers in flight per node ----
    {
        float wd0 = wd[2*lane], wd1 = wd[2*lane+1];
        const unsigned* c2 = (const unsigned*)c_rd + (size_t)batch*N_*(H_/2);
        const unsigned* a2 = (const unsigned*)a;
#pragma unroll
        for (int nn = 0; nn < 2; ++nn) {
            int m = wave*2 + nn;
            unsigned av = a2[(size_t)(node0+m)*(H_/2) + lane];
            float a0 = b2f((short)(av & 0xFFFFu)), a1 = b2f((short)(av >> 16));
            unsigned cva[16], cvb[16];
#pragma unroll
            for (int k = 0; k < 16; ++k)
                cva[k] = c2[(size_t)idx_s[m][k]*(H_/2) + lane];
#pragma unroll
            for (int k = 0; k < 16; ++k)
                cvb[k] = c2[(size_t)idx_s[m][16+k]*(H_/2) + lane];
            float s0 = 0.f, s1 = 0.f;
#pragma unroll
            for (int k = 0; k < 16; ++k) {
                float dd = dst_s[m][k];
                s0 += silu_f(a0 + fmaf(dd, wd0, b2f((short)(cva[k] & 0xFFFFu))));
                s1 += silu_f(a1 + fmaf(dd, wd1, b2f((short)(cva[k] >> 16))));
            }
#pragma unroll
            for (int k = 0; k < 16; ++k) {
                float dd = dst_s[m][16+k];
                s0 += silu_f(a0 + fmaf(dd, wd0, b2f((short)(cvb[k] & 0xFFFFu))));
                s1 += silu_f(a1 + fmaf(dd, wd1, b2f((short)(cvb[k] >> 16))));
            }
            *(unsigned*)&s_l[m][2*lane] = pack2(f2b(s0), f2b(s1));
        }
    }
    __syncthreads();

    f32x4 acc;
    // ---- GEMM1 ----
    acc = (f32x4){0,0,0,0};
#pragma unroll
    for (int kk = 0; kk < 4; ++kk) {
        int k0 = kk*32 + quad*8;
        short8 af = *(const short8*)&s_l[l15][k0];
        acc = __builtin_amdgcn_mfma_f32_16x16x32_bf16(af, bw2[kk], acc, 0, 0, 0);
    }
    {
        float b2v = b2[ncol] * (float)K_;
#pragma unroll
        for (int r = 0; r < 4; ++r)
            agg_l[quad*4 + r][ncol] = f2b(acc[r] + b2v);
    }
    __syncthreads();

    // ---- GEMM2 ----
    acc = (f32x4){0,0,0,0};
#pragma unroll
    for (int kk = 0; kk < 8; ++kk) {
        const short (*src)[LDW] = (kk < 4) ? h_l : agg_l;
        int kloc = ((kk < 4) ? kk*32 : (kk-4)*32) + quad*8;
        short8 af = *(const short8*)&src[l15][kloc];
        acc = __builtin_amdgcn_mfma_f32_16x16x32_bf16(af, bu1[kk], acc, 0, 0, 0);
    }
    short8 bacA[4], bacC[4];
    if (do_ac) {
#pragma unroll
        for (int kk = 0; kk < 4; ++kk) {
            bacA[kk] = *(const short8*)(wn + OFF_W1A + (size_t)ncol*H_ + kk*32 + quad*8);
            bacC[kk] = *(const short8*)(wn + OFF_W1C + (size_t)ncol*H_ + kk*32 + quad*8);
        }
    }
    {
        float u1bv = u1b[ncol];
#pragma unroll
        for (int r = 0; r < 4; ++r)
            s_l[quad*4 + r][ncol] = f2b(silu_f(acc[r] + u1bv));
    }
    __syncthreads();

    // ---- GEMM3 + residual ----
    acc = (f32x4){0,0,0,0};
#pragma unroll
    for (int kk = 0; kk < 4; ++kk) {
        int k0 = kk*32 + quad*8;
        short8 af = *(const short8*)&s_l[l15][k0];
        acc = __builtin_amdgcn_mfma_f32_16x16x32_bf16(af, bu2[kk], acc, 0, 0, 0);
    }
    {
        float u2bv = u2b[ncol];
#pragma unroll
        for (int r = 0; r < 4; ++r) {
            int m = quad*4 + r;
            float nh = h32s[m][ncol] + acc[r] + u2bv;
            h[(size_t)(node0+m)*H_ + ncol] = nh;
            if (do_ac) h_l[m][ncol] = f2b(nh);
            else       h32s[m][ncol] = nh;
        }
    }
    if (do_ac) {
        __syncthreads();
        int n = ncol;
        f32x4 accA = (f32x4){0,0,0,0}, accC = (f32x4){0,0,0,0};
#pragma unroll
        for (int kk = 0; kk < 4; ++kk) {
            int k0 = kk*32 + quad*8;
            short8 af = *(const short8*)&h_l[l15][k0];
            accA = __builtin_amdgcn_mfma_f32_16x16x32_bf16(af, bacA[kk], accA, 0, 0, 0);
            accC = __builtin_amdgcn_mfma_f32_16x16x32_bf16(af, bacC[kk], accC, 0, 0, 0);
        }
        float b1v = b1n[n];
#pragma unroll
        for (int r = 0; r < 4; ++r) {
            int m = quad*4 + r;
            size_t gi = (size_t)(node0+m)*H_ + n;
            a[gi]    = f2b(accA[r] + b1v);
            c_wr[gi] = f2b(accC[r]);
        }
    } else {
        __syncthreads();
        if (tid < NPB_L*OUT_) {
            int node = tid / OUT_, o = tid - node*OUT_;
            float accv = ob[o];
            for (int r = 0; r < H_; ++r)
                accv = fmaf(h32s[node][r], ow[r*OUT_ + o], accv);
            out[(size_t)(node0+node)*OUT_ + o] = accv;
        }
    }
}

extern "C" void kernel_launch(void* const* d_in, const int* in_sizes, int n_in,
                              void* d_out, int out_size, void* d_ws, size_t ws_size,
                              hipStream_t stream)
{
    const float* x   = (const float*)d_in[0];
    const float* ew  = (const float*)d_in[1];
    const float* eb  = (const float*)d_in[2];
    const float* miw = (const float*)d_in[3];
    const float* mib = (const float*)d_in[4];
    const float* mow = (const float*)d_in[5];
    const float* mob = (const float*)d_in[6];
    const float* uiw = (const float*)d_in[7];
    const float* uib = (const float*)d_in[8];
    const float* uow = (const float*)d_in[9];
    const float* uob = (const float*)d_in[10];
    const float* ow  = (const float*)d_in[11];
    const float* ob  = (const float*)d_in[12];
    float* out = (float*)d_out;

    // workspace: h fp32 | nd fp32 | ni i32 | a bf16 | c0 bf16 | c1 bf16 | wt bf16 | Epack fp32
    char* w = (char*)d_ws;
    float* h  = (float*)w;                         w += (size_t)BN_*H_*4;
    float* nd = (float*)w;                         w += (size_t)BN_*K_*4;
    int*   ni = (int*)w;                           w += (size_t)BN_*K_*4;
    short* a  = (short*)w;                         w += (size_t)BN_*H_*2;
    short* c0 = (short*)w;                         w += (size_t)BN_*H_*2;
    short* c1 = (short*)w;                         w += (size_t)BN_*H_*2;
    short* wt = (short*)w;                         w += (size_t)L_*LAYER_W*2;
    float* Epack = (float*)w;                                               // 4 KB

    k_front<<<KNN_BLKS + PREP_BLKS + 1, 256, 0, stream>>>(x, ni, nd,
        miw, mow, uiw, uow, wt, ew, eb, mib, Epack);
    // layer 0: fused embed + edge-from-x + ac(1); writes c1
    k_layer0<<<BN_/NPB_L, LBLK, 0, stream>>>(h, a, ni, nd,
        miw + 256*H_, wt,
        mob, uib, uob,
        c1, wt + LAYER_W, mib + H_,
        x, ew, eb, Epack);
    for (int l = 1; l < L_; ++l) {
        const short* c_rd = (l & 1) ? c1 : c0;
        short*       c_wr = (l & 1) ? c0 : c1;
        int do_ac = (l + 1 < L_);
        const short* wn = wt + (size_t)(do_ac ? (l+1) : l) * LAYER_W;
        const float* b1n = mib + (size_t)(do_ac ? (l+1) : l) * H_;
        k_layer<<<BN_/NPB_L, LBLK, 0, stream>>>(h, a, ni, nd,
            miw + (size_t)l*257*H_ + 256*H_,
            wt + (size_t)l*LAYER_W,
            mob + (size_t)l*H_, uib + (size_t)l*H_, uob + (size_t)l*H_,
            c_rd, c_wr, wn, b1n, do_ac,
            ow, ob, out);
    }
}